// Round 7
// baseline (619.532 us; speedup 1.0000x reference)
//
#include <hip/hip_runtime.h>
#include <stdint.h>

#define V_N    4096
#define NNZ_N  36864
#define S_N    216        // X*Y*Z = 6*6*6
#define ST_TOT 27         // S_N / 8
#define PLANES 256        // K * FIN
#define BPLANES 224       // basis planes per stl (k=1..7)

typedef float  f32x2 __attribute__((ext_vector_type(2)));
typedef float  f32x4 __attribute__((ext_vector_type(4)));
typedef short  s16x4 __attribute__((ext_vector_type(4)));
typedef short  s16x8 __attribute__((ext_vector_type(8)));

static __device__ __forceinline__ unsigned short f2bf(float f){
    union { float f; unsigned u; } x; x.f = f;
    unsigned r = x.u + 0x7FFFu + ((x.u >> 16) & 1u);   // round-to-nearest-even
    return (unsigned short)(r >> 16);
}
static __device__ __forceinline__ unsigned packbf(float lo, float hi){
    unsigned r;
    asm("v_cvt_pk_bf16_f32 %0, %1, %2" : "=v"(r) : "v"(lo), "v"(hi));
    return r;
}
static __device__ __forceinline__ void pkfma(f32x2& acc, f32x2 c, f32x2 vv){
    asm("v_pk_fma_f32 %0, %1, %2, %0" : "+v"(acc) : "v"(c), "v"(vv));
}
#define BLO(u) __uint_as_float((u) << 16)
#define BHI(u) __uint_as_float((u) & 0xFFFF0000u)

// ---------------- k_prep: fused hist + degree-sort + group offsets (1 block) --------
__global__ __launch_bounds__(1024) void k_prep(
    const int* __restrict__ rows, int* __restrict__ row_order,
    int* __restrict__ sp, int* __restrict__ gcnt, int* __restrict__ goff,
    int* __restrict__ rcur)
{
    __shared__ int cnt[4096];
    __shared__ int c2[4096];
    __shared__ int dh[64];
    int t = threadIdx.x;
    #pragma unroll
    for (int i = 0; i < 4; ++i) cnt[t + i*1024] = 0;
    if (t < 64) dh[t] = 0;
    __syncthreads();
    for (int e = t; e < NNZ_N; e += 1024) atomicAdd(&cnt[rows[e]], 1);
    __syncthreads();
    #pragma unroll
    for (int i = 0; i < 4; ++i){
        int d = cnt[t + i*1024]; if (d > 63) d = 63;
        atomicAdd(&dh[d], 1);
    }
    __syncthreads();
    if (t == 0){ int s = 0; for (int i = 0; i < 64; ++i){ int x = dh[i]; dh[i] = s; s += x; } }
    __syncthreads();
    #pragma unroll
    for (int i = 0; i < 4; ++i){
        int v = t + i*1024;
        int d = cnt[v]; int db = d > 63 ? 63 : d;
        int pos = atomicAdd(&dh[db], 1);
        row_order[pos] = v; sp[v] = pos; c2[pos] = d;
    }
    #pragma unroll
    for (int i = 0; i < 4; ++i) rcur[t + i*1024] = 0;
    __syncthreads();
    if (t == 0){
        int off = 0;
        for (int g = 0; g < 64; ++g){
            int d = c2[g*64 + 63]; if (d > 64) d = 64;
            gcnt[g] = d; goff[g] = off; off += (d + 3) * 64;
        }
    }
}

// ---------------- k_fill2: ELL fill (blocks 0..143) + W pack (blocks 144..175) ------
__global__ void k_fill2(const int* __restrict__ rows, const int* __restrict__ cols,
                        const float* __restrict__ vals, const int* __restrict__ sp,
                        const int* __restrict__ gcnt, const int* __restrict__ goff,
                        int* __restrict__ rcur, unsigned* __restrict__ ell,
                        const float* __restrict__ w, unsigned short* __restrict__ wtab)
{
    int bid = blockIdx.x, t = threadIdx.x;
    if (bid < 144){
        int e = bid * 256 + t;
        if (e < NNZ_N){
            int r = rows[e]; int s = sp[r]; int g = s >> 6; int l = s & 63;
            int i = atomicAdd(&rcur[r], 1);
            if (i < gcnt[g])
                ell[goff[g] + i * 64 + l] =
                    ((unsigned)cols[e] << 4) | ((unsigned)f2bf(vals[e]) << 16);
        }
    } else {
        int idx = (bid - 144) * 256 + t;   // 0..8191
        int slot = idx >> 3, j = idx & 7;
        int ki = slot >> 7, nh = (slot >> 6) & 1, l = slot & 63;
        int p  = ki * 32 + ((l >> 4) << 3) + j;
        int fo = nh * 16 + (l & 15);
        wtab[idx] = f2bf(w[p * 32 + fo]);
    }
}

// ---------------- k_pre: input transpose -> t0 planes (bf16), ALL stl once --------
// t0 layout: t0[(stl*32 + f)*4096 + v] (uint4 = 8 sl)
__global__ __launch_bounds__(256, 4) void k_pre(
    const float* __restrict__ in, uint4* __restrict__ t0)
{
    __shared__ unsigned short lds[64 * 218];   // 27.3 KB, row stride 436 B
    int bid = blockIdx.x;
    int f = bid >> 6, vblk = bid & 63;
    int t = threadIdx.x;
    const f32x4* src = (const f32x4*)(in + ((size_t)f * V_N + vblk * 64) * S_N);

    #pragma unroll
    for (int it = 0; it < 14; ++it){
        int idx = t + it * 256;                 // float4 index, 0..3455
        if (idx < 3456){
            int vloc = (int)(((unsigned)idx * 4855u) >> 18);   // idx / 54
            int s4   = idx - vloc * 54;
            f32x4 a = __builtin_nontemporal_load(&src[idx]);
            uint2 q; q.x = packbf(a.x, a.y); q.y = packbf(a.z, a.w);
            *(uint2*)((char*)lds + vloc * 436 + s4 * 8) = q;
        }
    }
    __syncthreads();
    #pragma unroll
    for (int it = 0; it < 7; ++it){
        int idx = t + it * 256;
        if (idx < ST_TOT * 64){
            int stl = idx >> 6, vl = idx & 63;
            uint4 q = *(const uint4*)((const char*)lds + vl * 436 + stl * 16);
            t0[(((size_t)(stl * 32 + f)) << 12) + vblk * 64 + vl] = q;
        }
    }
}

// ---------------- Phase A: LDS-resident Chebyshev recurrence ----------------
// basis (chunk-local): basis[(stl*224 + (k-1)*32 + f)*4096 + v]
__global__ __launch_bounds__(1024, 8) void k_phaseA(
    const int* __restrict__ row_order,
    const int* __restrict__ goff, const int* __restrict__ gcnt,
    const unsigned* __restrict__ ell, const uint4* __restrict__ t0,
    uint4* __restrict__ basis, int st0)
{
    __shared__ uint4 T4[V_N];        // 64 KB
    int f   = blockIdx.x & 31;
    int stl = blockIdx.x >> 5;       // chunk-local
    int st_g = st0 + stl;            // global
    int t = threadIdx.x;

    // T0 from t0 (coalesced 64 KB read) -> LDS
    const uint4* t0p = t0 + (((size_t)(st_g * 32 + f)) << 12);
    #pragma unroll
    for (int rr = 0; rr < 4; ++rr){
        int v = t + rr * 1024;
        T4[v] = t0p[v];
    }
    __syncthreads();

    // wave w owns groups {w, w+16, w+32, w+48}  (strided => balanced degrees)
    int w = t >> 6, lane = t & 63;
    int vr[4], gba[4], gcn[4];
    #pragma unroll
    for (int rr = 0; rr < 4; ++rr){
        int g = w + rr * 16;
        vr[rr]  = row_order[g * 64 + lane];
        gba[rr] = goff[g] + lane;
        gcn[rr] = __builtin_amdgcn_readfirstlane(gcnt[g]);
    }
    uint4 tm2[4];
    #pragma unroll
    for (int rr = 0; rr < 4; ++rr) tm2[rr] = T4[vr[rr]];   // T0 own rows

    for (int k = 1; k < 8; ++k){
        uint4 nst[4];
        #pragma unroll
        for (int rr = 0; rr < 4; ++rr){
            f32x2 ac0 = {0,0}, ac1 = {0,0}, ac2 = {0,0}, ac3 = {0,0};
            const unsigned* ep = ell + gba[rr];
            int cnt = gcn[rr];
            unsigned u0 = ep[0];
            unsigned u1 = ep[64];
            for (int i = 0; i < cnt; i += 2){
                unsigned n0 = ep[(i + 2) << 6];     // prefetch next pair (pad rows are 0)
                unsigned n1 = ep[(i + 3) << 6];
                uint4 q0 = *(const uint4*)((const char*)T4 + (u0 & 0xFFF0u));
                uint4 q1 = *(const uint4*)((const char*)T4 + (u1 & 0xFFF0u));
                float v0 = __uint_as_float(u0 & 0xFFFF0000u);
                float v1 = __uint_as_float(u1 & 0xFFFF0000u);
                f32x2 vv0 = {v0, v0};
                f32x2 vv1 = {v1, v1};
                f32x2 c;
                c.x = BLO(q0.x); c.y = BHI(q0.x);  pkfma(ac0, c, vv0);
                c.x = BLO(q0.y); c.y = BHI(q0.y);  pkfma(ac1, c, vv0);
                c.x = BLO(q0.z); c.y = BHI(q0.z);  pkfma(ac2, c, vv0);
                c.x = BLO(q0.w); c.y = BHI(q0.w);  pkfma(ac3, c, vv0);
                c.x = BLO(q1.x); c.y = BHI(q1.x);  pkfma(ac0, c, vv1);
                c.x = BLO(q1.y); c.y = BHI(q1.y);  pkfma(ac1, c, vv1);
                c.x = BLO(q1.z); c.y = BHI(q1.z);  pkfma(ac2, c, vv1);
                c.x = BLO(q1.w); c.y = BHI(q1.w);  pkfma(ac3, c, vv1);
                u0 = n0; u1 = n1;
            }
            float a0 = ac0.x, a1 = ac0.y, a2 = ac1.x, a3 = ac1.y;
            float a4 = ac2.x, a5 = ac2.y, a6 = ac3.x, a7 = ac3.y;
            if (k > 1){
                a0 = fmaf(2.f, a0, -BLO(tm2[rr].x));  a1 = fmaf(2.f, a1, -BHI(tm2[rr].x));
                a2 = fmaf(2.f, a2, -BLO(tm2[rr].y));  a3 = fmaf(2.f, a3, -BHI(tm2[rr].y));
                a4 = fmaf(2.f, a4, -BLO(tm2[rr].z));  a5 = fmaf(2.f, a5, -BHI(tm2[rr].z));
                a6 = fmaf(2.f, a6, -BLO(tm2[rr].w));  a7 = fmaf(2.f, a7, -BHI(tm2[rr].w));
            }
            nst[rr].x = packbf(a0, a1); nst[rr].y = packbf(a2, a3);
            nst[rr].z = packbf(a4, a5); nst[rr].w = packbf(a6, a7);
        }
        #pragma unroll
        for (int rr = 0; rr < 4; ++rr) tm2[rr] = T4[vr[rr]];   // T_{k-1} own rows
        __syncthreads();
        #pragma unroll
        for (int rr = 0; rr < 4; ++rr) T4[vr[rr]] = nst[rr];   // LDS <- T_k
        __syncthreads();
        // coalesced basis write of T_k from LDS (natural row order)
        size_t pb = ((size_t)(stl * BPLANES + (k - 1) * 32 + f)) << 12;
        #pragma unroll
        for (int rr = 0; rr < 4; ++rr){
            int v = t + rr * 1024;
            basis[pb + v] = T4[v];
        }
    }
}

// ---------------- Phase B: projection GEMM (MFMA bf16), 64 rows/block ----------------
__global__ __launch_bounds__(256, 3) void k_phaseB(
    const uint4* __restrict__ basis, const uint4* __restrict__ t0,
    const uint4* __restrict__ wtab, const float* __restrict__ bias,
    float* __restrict__ out, int st0)
{
    __shared__ uint4 A[2048];      // 32 KB
    __shared__ uint4 WL[1088];     // 17 KB (W; reused as outT in epilogue)
    int t = threadIdx.x;
    int tile = blockIdx.x;
    int stl = tile >> 9, vb = tile & 511;
    int st_g = st0 + stl;

    // stage A (64 rows x 256 planes) with tr_b16 permutation + W table
    const uint4* gB = basis + (((size_t)(stl * BPLANES)) << 12) + vb * 8;
    const uint4* gT = t0 + (((size_t)(st_g * 32)) << 12) + vb * 8;
    #pragma unroll
    for (int it = 0; it < 8; ++it){
        int g = (it << 8) + t;
        int p = g >> 3, vrr = g & 7;
        uint4 q = (p < 32) ? gT[((size_t)p << 12) + vrr]
                           : gB[((size_t)(p - 32) << 12) + vrr];
        int b = ((vrr >> 2) << 10) + (((vrr >> 1) & 1) << 9)
              + ((p >> 5) << 6) + (((p >> 2) & 1) << 5) + (((p >> 3) & 3) << 3)
              + ((p & 3) << 1) + (vrr & 1);
        A[b] = q;
    }
    #pragma unroll
    for (int it = 0; it < 4; ++it) WL[(it << 8) + t] = wtab[(it << 8) + t];
    __syncthreads();

    int lane = t & 63, w = t >> 6;
    // preload W fragments to VGPR; after barrier WL is dead (becomes outT)
    s16x8 wf[16];
    #pragma unroll
    for (int q = 0; q < 16; ++q) wf[q] = *(const s16x8*)&WL[(q << 6) + lane];
    __syncthreads();

    unsigned abase = (unsigned)(size_t)(&A[0]) + ((w >> 1) << 14) + ((w & 1) << 13) + (lane << 3);
    f32x4 acc0 = {0,0,0,0}, acc1 = {0,0,0,0};
    #pragma unroll
    for (int ki = 0; ki < 8; ++ki){
        s16x4 x0, x1;
        unsigned a0 = abase + (ki << 10);
        asm volatile("ds_read_b64_tr_b16 %0, %2\n\t"
                     "ds_read_b64_tr_b16 %1, %2 offset:512\n\t"
                     "s_waitcnt lgkmcnt(0)"
                     : "=&v"(x0), "=&v"(x1) : "v"(a0));
        __builtin_amdgcn_sched_barrier(0);
        s16x8 af;
        af[0]=x0[0]; af[1]=x0[1]; af[2]=x0[2]; af[3]=x0[3];
        af[4]=x1[0]; af[5]=x1[1]; af[6]=x1[2]; af[7]=x1[3];
        acc0 = __builtin_amdgcn_mfma_f32_16x16x32_bf16(af, wf[2*ki+0], acc0, 0, 0, 0);
        acc1 = __builtin_amdgcn_mfma_f32_16x16x32_bf16(af, wf[2*ki+1], acc1, 0, 0, 0);
    }

    // stage 64x32 output tile into WL region, then fully-coalesced store
    float* outT = (float*)&WL[0];     // [fo][68] floats (8.7 KB)
    {
        int rl0 = w * 16 + ((lane >> 4) << 2);
        int foA = lane & 15, foB = 16 + (lane & 15);
        float2 p;
        p.x = acc0[0]; p.y = acc0[1]; *(float2*)&outT[foA*68 + rl0]     = p;
        p.x = acc0[2]; p.y = acc0[3]; *(float2*)&outT[foA*68 + rl0 + 2] = p;
        p.x = acc1[0]; p.y = acc1[1]; *(float2*)&outT[foB*68 + rl0]     = p;
        p.x = acc1[2]; p.y = acc1[3]; *(float2*)&outT[foB*68 + rl0 + 2] = p;
    }
    __syncthreads();
    {
        int fo = t >> 3;
        int rl = (t & 7) << 3;            // 8 rows = 1 v, all 8 sl
        float bs = bias[fo];
        float2 q0 = *(const float2*)&outT[fo*68 + rl];
        float2 q1 = *(const float2*)&outT[fo*68 + rl + 2];
        float2 q2 = *(const float2*)&outT[fo*68 + rl + 4];
        float2 q3 = *(const float2*)&outT[fo*68 + rl + 6];
        int v = vb * 8 + (t & 7);
        float* gb = out + ((size_t)fo * V_N + v) * S_N + st_g * 8;
        f32x4 o;
        o.x = q0.x + bs; o.y = q0.y + bs; o.z = q1.x + bs; o.w = q1.y + bs;
        __builtin_nontemporal_store(o, (f32x4*)gb);
        o.x = q2.x + bs; o.y = q2.y + bs; o.z = q3.x + bs; o.w = q3.y + bs;
        __builtin_nontemporal_store(o, (f32x4*)(gb + 4));
    }
}

// ---------------- host ----------------
extern "C" void kernel_launch(void* const* d_in, const int* in_sizes, int n_in,
                              void* d_out, int out_size, void* d_ws, size_t ws_size,
                              hipStream_t stream)
{
    const float* inp  = (const float*)d_in[0];
    const float* wgt  = (const float*)d_in[1];
    const float* bias = (const float*)d_in[2];
    const float* vals = (const float*)d_in[3];
    const int*   rows = (const int*)d_in[4];
    const int*   cols = (const int*)d_in[5];
    float* out = (float*)d_out;

    char* ws = (char*)d_ws;
    size_t o = 0;
    auto alloc = [&](size_t bytes) -> void* {
        void* p = ws + o; o = (o + bytes + 255) & ~(size_t)255; return p;
    };
    const size_t ELL_B = (size_t)64 * 67 * 64 * 4;   // 1.05 MB hard cap
    int* row_order = (int*)alloc(4096 * 4);
    int* sp        = (int*)alloc(4096 * 4);
    int* gcnt      = (int*)alloc(64 * 4);
    int* goff      = (int*)alloc(64 * 4);
    int* rcur      = (int*)alloc(4096 * 4);
    unsigned* ell  = (unsigned*)alloc(ELL_B);
    uint4* wtab    = (uint4*)alloc(8192 * 2);
    uint4* t0buf   = (uint4*)alloc((size_t)ST_TOT * 32 * V_N * 16);   // 56.6 MB
    size_t used = o;

    size_t per_st = (size_t)BPLANES * V_N * 16;      // 14.68 MB per s8-tile
    size_t avail = (ws_size > used) ? (ws_size - used) : 0;
    int tiles_c = (int)(avail / per_st);
    if (tiles_c > 16) tiles_c = 16;                  // {16,11} chunk pattern
    if (tiles_c < 1) tiles_c = 1;
    uint4* basis = (uint4*)alloc(per_st * tiles_c);  // chunk-local, region-reused

    hipMemsetAsync(ell, 0, ELL_B, stream);
    k_prep  <<<1, 1024, 0, stream>>>(rows, row_order, sp, gcnt, goff, rcur);
    k_fill2 <<<176, 256, 0, stream>>>(rows, cols, vals, sp, gcnt, goff, rcur, ell,
                                      wgt, (unsigned short*)wtab);
    k_pre   <<<2048, 256, 0, stream>>>(inp, t0buf);

    for (int st0 = 0; st0 < ST_TOT; st0 += tiles_c){
        int tc = ST_TOT - st0; if (tc > tiles_c) tc = tiles_c;
        k_phaseA<<<32 * tc, 1024, 0, stream>>>(row_order, goff, gcnt, ell, t0buf, basis, st0);
        k_phaseB<<<tc * 512, 256, 0, stream>>>(basis, t0buf, wtab, bias, out, st0);
    }
}

// Round 8
// 615.031 us; speedup vs baseline: 1.0073x; 1.0073x over previous
//
#include <hip/hip_runtime.h>
#include <stdint.h>

#define V_N    4096
#define NNZ_N  36864
#define S_N    216        // X*Y*Z = 6*6*6
#define ST_TOT 27         // S_N / 8
#define PLANES 256        // K * FIN
#define BPLANES 224       // basis planes per stl (k=1..7)

typedef float  f32x2 __attribute__((ext_vector_type(2)));
typedef float  f32x4 __attribute__((ext_vector_type(4)));
typedef short  s16x4 __attribute__((ext_vector_type(4)));
typedef short  s16x8 __attribute__((ext_vector_type(8)));

static __device__ __forceinline__ unsigned short f2bf(float f){
    union { float f; unsigned u; } x; x.f = f;
    unsigned r = x.u + 0x7FFFu + ((x.u >> 16) & 1u);   // round-to-nearest-even
    return (unsigned short)(r >> 16);
}
static __device__ __forceinline__ unsigned packbf(float lo, float hi){
    unsigned r;
    asm("v_cvt_pk_bf16_f32 %0, %1, %2" : "=v"(r) : "v"(lo), "v"(hi));
    return r;
}
static __device__ __forceinline__ void pkfma(f32x2& acc, f32x2 c, f32x2 vv){
    asm("v_pk_fma_f32 %0, %1, %2, %0" : "+v"(acc) : "v"(c), "v"(vv));
}
static __device__ __forceinline__ void gld_lds16(const void* g, void* l){
    __builtin_amdgcn_global_load_lds(
        (const __attribute__((address_space(1))) void*)(g),
        (__attribute__((address_space(3))) void*)(l), 16, 0, 0);
}
#define BLO(u) __uint_as_float((u) << 16)
#define BHI(u) __uint_as_float((u) & 0xFFFF0000u)

// ---------------- k_prep: fused hist + degree-sort + group offsets (1 block) --------
__global__ __launch_bounds__(1024) void k_prep(
    const int* __restrict__ rows, int* __restrict__ row_order,
    int* __restrict__ sp, int* __restrict__ gcnt, int* __restrict__ goff,
    int* __restrict__ rcur)
{
    __shared__ int cnt[4096];
    __shared__ int c2[4096];
    __shared__ int dh[64];
    int t = threadIdx.x;
    #pragma unroll
    for (int i = 0; i < 4; ++i) cnt[t + i*1024] = 0;
    if (t < 64) dh[t] = 0;
    __syncthreads();
    for (int e = t; e < NNZ_N; e += 1024) atomicAdd(&cnt[rows[e]], 1);
    __syncthreads();
    #pragma unroll
    for (int i = 0; i < 4; ++i){
        int d = cnt[t + i*1024]; if (d > 63) d = 63;
        atomicAdd(&dh[d], 1);
    }
    __syncthreads();
    if (t == 0){ int s = 0; for (int i = 0; i < 64; ++i){ int x = dh[i]; dh[i] = s; s += x; } }
    __syncthreads();
    #pragma unroll
    for (int i = 0; i < 4; ++i){
        int v = t + i*1024;
        int d = cnt[v]; int db = d > 63 ? 63 : d;
        int pos = atomicAdd(&dh[db], 1);
        row_order[pos] = v; sp[v] = pos; c2[pos] = d;
    }
    #pragma unroll
    for (int i = 0; i < 4; ++i) rcur[t + i*1024] = 0;
    __syncthreads();
    if (t == 0){
        int off = 0;
        for (int g = 0; g < 64; ++g){
            int d = c2[g*64 + 63]; if (d > 64) d = 64;
            gcnt[g] = d; goff[g] = off; off += (d + 3) * 64;
        }
    }
}

// ---------------- k_fill2: ELL fill (blocks 0..143) + W pack (blocks 144..175) ------
__global__ void k_fill2(const int* __restrict__ rows, const int* __restrict__ cols,
                        const float* __restrict__ vals, const int* __restrict__ sp,
                        const int* __restrict__ gcnt, const int* __restrict__ goff,
                        int* __restrict__ rcur, unsigned* __restrict__ ell,
                        const float* __restrict__ w, unsigned short* __restrict__ wtab)
{
    int bid = blockIdx.x, t = threadIdx.x;
    if (bid < 144){
        int e = bid * 256 + t;
        if (e < NNZ_N){
            int r = rows[e]; int s = sp[r]; int g = s >> 6; int l = s & 63;
            int i = atomicAdd(&rcur[r], 1);
            if (i < gcnt[g])
                ell[goff[g] + i * 64 + l] =
                    ((unsigned)cols[e] << 4) | ((unsigned)f2bf(vals[e]) << 16);
        }
    } else {
        int idx = (bid - 144) * 256 + t;   // 0..8191
        int slot = idx >> 3, j = idx & 7;
        int ki = slot >> 7, nh = (slot >> 6) & 1, l = slot & 63;
        int p  = ki * 32 + ((l >> 4) << 3) + j;
        int fo = nh * 16 + (l & 15);
        wtab[idx] = f2bf(w[p * 32 + fo]);
    }
}

// ---------------- k_pre: input transpose -> t0 planes (bf16), ALL stl once --------
// t0 layout: t0[(stl*32 + f)*4096 + v] (uint4 = 8 sl)
__global__ __launch_bounds__(256, 4) void k_pre(
    const float* __restrict__ in, uint4* __restrict__ t0)
{
    __shared__ unsigned short lds[64 * 218];   // 27.3 KB, row stride 436 B
    int bid = blockIdx.x;
    int f = bid >> 6, vblk = bid & 63;
    int t = threadIdx.x;
    const f32x4* src = (const f32x4*)(in + ((size_t)f * V_N + vblk * 64) * S_N);

    #pragma unroll
    for (int it = 0; it < 14; ++it){
        int idx = t + it * 256;                 // float4 index, 0..3455
        if (idx < 3456){
            int vloc = (int)(((unsigned)idx * 4855u) >> 18);   // idx / 54
            int s4   = idx - vloc * 54;
            f32x4 a = __builtin_nontemporal_load(&src[idx]);
            uint2 q; q.x = packbf(a.x, a.y); q.y = packbf(a.z, a.w);
            *(uint2*)((char*)lds + vloc * 436 + s4 * 8) = q;
        }
    }
    __syncthreads();
    #pragma unroll
    for (int it = 0; it < 7; ++it){
        int idx = t + it * 256;
        if (idx < ST_TOT * 64){
            int stl = idx >> 6, vl = idx & 63;
            uint4 q = *(const uint4*)((const char*)lds + vl * 436 + stl * 16);
            t0[(((size_t)(stl * 32 + f)) << 12) + vblk * 64 + vl] = q;
        }
    }
}

// ---------------- Phase A: LDS-resident Chebyshev recurrence ----------------
// basis (chunk-local): basis[(stl*224 + (k-1)*32 + f)*4096 + v]
__global__ __launch_bounds__(1024, 8) void k_phaseA(
    const int* __restrict__ row_order,
    const int* __restrict__ goff, const int* __restrict__ gcnt,
    const unsigned* __restrict__ ell, const uint4* __restrict__ t0,
    uint4* __restrict__ basis, int st0)
{
    __shared__ uint4 T4[V_N];        // 64 KB
    int f   = blockIdx.x & 31;
    int stl = blockIdx.x >> 5;       // chunk-local
    int st_g = st0 + stl;            // global
    int t = threadIdx.x;

    // T0 from t0 (coalesced 64 KB read) -> LDS
    const uint4* t0p = t0 + (((size_t)(st_g * 32 + f)) << 12);
    #pragma unroll
    for (int rr = 0; rr < 4; ++rr){
        int v = t + rr * 1024;
        T4[v] = t0p[v];
    }
    __syncthreads();

    // wave w owns groups {w, w+16, w+32, w+48}  (strided => balanced degrees)
    int w = t >> 6, lane = t & 63;
    int vr[4], gba[4], gcn[4];
    #pragma unroll
    for (int rr = 0; rr < 4; ++rr){
        int g = w + rr * 16;
        vr[rr]  = row_order[g * 64 + lane];
        gba[rr] = goff[g] + lane;
        gcn[rr] = __builtin_amdgcn_readfirstlane(gcnt[g]);
    }
    uint4 tm2[4];
    #pragma unroll
    for (int rr = 0; rr < 4; ++rr) tm2[rr] = T4[vr[rr]];   // T0 own rows

    for (int k = 1; k < 8; ++k){
        uint4 nst[4];
        #pragma unroll
        for (int rr = 0; rr < 4; ++rr){
            f32x2 ac0 = {0,0}, ac1 = {0,0}, ac2 = {0,0}, ac3 = {0,0};
            const unsigned* ep = ell + gba[rr];
            int cnt = gcn[rr];
            unsigned u0 = ep[0];
            unsigned u1 = ep[64];
            for (int i = 0; i < cnt; i += 2){
                unsigned n0 = ep[(i + 2) << 6];     // prefetch next pair (pad rows are 0)
                unsigned n1 = ep[(i + 3) << 6];
                uint4 q0 = *(const uint4*)((const char*)T4 + (u0 & 0xFFF0u));
                uint4 q1 = *(const uint4*)((const char*)T4 + (u1 & 0xFFF0u));
                float v0 = __uint_as_float(u0 & 0xFFFF0000u);
                float v1 = __uint_as_float(u1 & 0xFFFF0000u);
                f32x2 vv0 = {v0, v0};
                f32x2 vv1 = {v1, v1};
                f32x2 c;
                c.x = BLO(q0.x); c.y = BHI(q0.x);  pkfma(ac0, c, vv0);
                c.x = BLO(q0.y); c.y = BHI(q0.y);  pkfma(ac1, c, vv0);
                c.x = BLO(q0.z); c.y = BHI(q0.z);  pkfma(ac2, c, vv0);
                c.x = BLO(q0.w); c.y = BHI(q0.w);  pkfma(ac3, c, vv0);
                c.x = BLO(q1.x); c.y = BHI(q1.x);  pkfma(ac0, c, vv1);
                c.x = BLO(q1.y); c.y = BHI(q1.y);  pkfma(ac1, c, vv1);
                c.x = BLO(q1.z); c.y = BHI(q1.z);  pkfma(ac2, c, vv1);
                c.x = BLO(q1.w); c.y = BHI(q1.w);  pkfma(ac3, c, vv1);
                u0 = n0; u1 = n1;
            }
            float a0 = ac0.x, a1 = ac0.y, a2 = ac1.x, a3 = ac1.y;
            float a4 = ac2.x, a5 = ac2.y, a6 = ac3.x, a7 = ac3.y;
            if (k > 1){
                a0 = fmaf(2.f, a0, -BLO(tm2[rr].x));  a1 = fmaf(2.f, a1, -BHI(tm2[rr].x));
                a2 = fmaf(2.f, a2, -BLO(tm2[rr].y));  a3 = fmaf(2.f, a3, -BHI(tm2[rr].y));
                a4 = fmaf(2.f, a4, -BLO(tm2[rr].z));  a5 = fmaf(2.f, a5, -BHI(tm2[rr].z));
                a6 = fmaf(2.f, a6, -BLO(tm2[rr].w));  a7 = fmaf(2.f, a7, -BHI(tm2[rr].w));
            }
            nst[rr].x = packbf(a0, a1); nst[rr].y = packbf(a2, a3);
            nst[rr].z = packbf(a4, a5); nst[rr].w = packbf(a6, a7);
        }
        #pragma unroll
        for (int rr = 0; rr < 4; ++rr) tm2[rr] = T4[vr[rr]];   // T_{k-1} own rows
        __syncthreads();
        #pragma unroll
        for (int rr = 0; rr < 4; ++rr) T4[vr[rr]] = nst[rr];   // LDS <- T_k
        __syncthreads();
        // coalesced basis write of T_k from LDS (natural row order)
        size_t pb = ((size_t)(stl * BPLANES + (k - 1) * 32 + f)) << 12;
        #pragma unroll
        for (int rr = 0; rr < 4; ++rr){
            int v = t + rr * 1024;
            basis[pb + v] = T4[v];
        }
    }
}

// ---------------- Phase B: projection GEMM (MFMA bf16), 64 rows/block -----------
// A staged via global_load_lds: linear LDS dest + bit-inverse-permuted global src
__global__ __launch_bounds__(256, 3) void k_phaseB(
    const uint4* __restrict__ basis, const uint4* __restrict__ t0,
    const uint4* __restrict__ wtab, const float* __restrict__ bias,
    float* __restrict__ out, int st0)
{
    __shared__ uint4 A[2048];      // 32 KB (permuted A tile; reused as nothing)
    __shared__ uint4 WL[1088];     // 17 KB (W; reused as outT in epilogue)
    int t = threadIdx.x;
    int tile = blockIdx.x;
    int stl = tile >> 9, vb = tile & 511;
    int st_g = st0 + stl;

    int lane = t & 63, w = t >> 6;
    // inverse permutation, separable: lane part (p_l, vrr_l), instr part (j*32, 2w)
    int p_l = (((lane >> 5) & 1) << 2) | (((lane >> 3) & 3) << 3) | ((lane >> 1) & 3);
    int vrr = (w << 1) | (lane & 1);
    const uint4* gT = t0 + (((size_t)(st_g * 32)) << 12) + vb * 8;
    const uint4* gB = basis + (((size_t)(stl * BPLANES)) << 12) + vb * 8;
    const uint4* srcT = gT + ((size_t)p_l << 12) + vrr;
    const uint4* srcB = gB + ((size_t)p_l << 12) + vrr;

    // A: 8 DMA instr/wave (j=0 from t0, j>=1 from basis planes (j-1)*32..)
    gld_lds16(srcT, &A[(w * 8) << 6]);
    #pragma unroll
    for (int j = 1; j < 8; ++j)
        gld_lds16(srcB + (((size_t)(j - 1)) << 17), &A[((w * 8 + j) << 6)]);
    // W: 4 DMA instr/wave, wtab already fragment-linear
    #pragma unroll
    for (int jj = 0; jj < 4; ++jj)
        gld_lds16(wtab + ((w * 4 + jj) << 6) + lane, &WL[(w * 4 + jj) << 6]);

    asm volatile("s_waitcnt vmcnt(0)" ::: "memory");
    __syncthreads();

    unsigned abase = (unsigned)(size_t)(&A[0]) + ((w >> 1) << 14) + ((w & 1) << 13) + (lane << 3);
    const char* wbase = (const char*)&WL[0];
    f32x4 acc0 = {0,0,0,0}, acc1 = {0,0,0,0};
    #pragma unroll
    for (int ki = 0; ki < 8; ++ki){
        s16x4 x0, x1;
        unsigned a0 = abase + (ki << 10);
        asm volatile("ds_read_b64_tr_b16 %0, %2\n\t"
                     "ds_read_b64_tr_b16 %1, %2 offset:512\n\t"
                     "s_waitcnt lgkmcnt(0)"
                     : "=&v"(x0), "=&v"(x1) : "v"(a0));
        __builtin_amdgcn_sched_barrier(0);
        s16x8 af;
        af[0]=x0[0]; af[1]=x0[1]; af[2]=x0[2]; af[3]=x0[3];
        af[4]=x1[0]; af[5]=x1[1]; af[6]=x1[2]; af[7]=x1[3];
        s16x8 b0 = *(const s16x8*)(wbase + (((ki * 2 + 0) << 6) + lane) * 16);
        s16x8 b1 = *(const s16x8*)(wbase + (((ki * 2 + 1) << 6) + lane) * 16);
        acc0 = __builtin_amdgcn_mfma_f32_16x16x32_bf16(af, b0, acc0, 0, 0, 0);
        acc1 = __builtin_amdgcn_mfma_f32_16x16x32_bf16(af, b1, acc1, 0, 0, 0);
    }

    // stage 64x32 output tile into WL region, then fully-coalesced store
    __syncthreads();
    float* outT = (float*)&WL[0];     // [fo][68] floats (8.7 KB)
    {
        int rl0 = w * 16 + ((lane >> 4) << 2);
        int foA = lane & 15, foB = 16 + (lane & 15);
        float2 p;
        p.x = acc0[0]; p.y = acc0[1]; *(float2*)&outT[foA*68 + rl0]     = p;
        p.x = acc0[2]; p.y = acc0[3]; *(float2*)&outT[foA*68 + rl0 + 2] = p;
        p.x = acc1[0]; p.y = acc1[1]; *(float2*)&outT[foB*68 + rl0]     = p;
        p.x = acc1[2]; p.y = acc1[3]; *(float2*)&outT[foB*68 + rl0 + 2] = p;
    }
    __syncthreads();
    {
        int fo = t >> 3;
        int rl = (t & 7) << 3;            // 8 rows = 1 v, all 8 sl
        float bs = bias[fo];
        float2 q0 = *(const float2*)&outT[fo*68 + rl];
        float2 q1 = *(const float2*)&outT[fo*68 + rl + 2];
        float2 q2 = *(const float2*)&outT[fo*68 + rl + 4];
        float2 q3 = *(const float2*)&outT[fo*68 + rl + 6];
        int v = vb * 8 + (t & 7);
        float* gb = out + ((size_t)fo * V_N + v) * S_N + st_g * 8;
        f32x4 o;
        o.x = q0.x + bs; o.y = q0.y + bs; o.z = q1.x + bs; o.w = q1.y + bs;
        __builtin_nontemporal_store(o, (f32x4*)gb);
        o.x = q2.x + bs; o.y = q2.y + bs; o.z = q3.x + bs; o.w = q3.y + bs;
        __builtin_nontemporal_store(o, (f32x4*)(gb + 4));
    }
}

// ---------------- host ----------------
extern "C" void kernel_launch(void* const* d_in, const int* in_sizes, int n_in,
                              void* d_out, int out_size, void* d_ws, size_t ws_size,
                              hipStream_t stream)
{
    const float* inp  = (const float*)d_in[0];
    const float* wgt  = (const float*)d_in[1];
    const float* bias = (const float*)d_in[2];
    const float* vals = (const float*)d_in[3];
    const int*   rows = (const int*)d_in[4];
    const int*   cols = (const int*)d_in[5];
    float* out = (float*)d_out;

    char* ws = (char*)d_ws;
    size_t o = 0;
    auto alloc = [&](size_t bytes) -> void* {
        void* p = ws + o; o = (o + bytes + 255) & ~(size_t)255; return p;
    };
    const size_t ELL_B = (size_t)64 * 67 * 64 * 4;   // 1.05 MB hard cap
    int* row_order = (int*)alloc(4096 * 4);
    int* sp        = (int*)alloc(4096 * 4);
    int* gcnt      = (int*)alloc(64 * 4);
    int* goff      = (int*)alloc(64 * 4);
    int* rcur      = (int*)alloc(4096 * 4);
    unsigned* ell  = (unsigned*)alloc(ELL_B);
    uint4* wtab    = (uint4*)alloc(8192 * 2);
    uint4* t0buf   = (uint4*)alloc((size_t)ST_TOT * 32 * V_N * 16);   // 56.6 MB
    size_t used = o;

    size_t per_st = (size_t)BPLANES * V_N * 16;      // 14.68 MB per s8-tile
    size_t avail = (ws_size > used) ? (ws_size - used) : 0;
    int tiles_c = (int)(avail / per_st);
    if (tiles_c > 16) tiles_c = 16;                  // {16,11} chunk pattern
    if (tiles_c < 1) tiles_c = 1;
    uint4* basis = (uint4*)alloc(per_st * tiles_c);  // chunk-local, region-reused

    hipMemsetAsync(ell, 0, ELL_B, stream);
    k_prep  <<<1, 1024, 0, stream>>>(rows, row_order, sp, gcnt, goff, rcur);
    k_fill2 <<<176, 256, 0, stream>>>(rows, cols, vals, sp, gcnt, goff, rcur, ell,
                                      wgt, (unsigned short*)wtab);
    k_pre   <<<2048, 256, 0, stream>>>(inp, t0buf);

    for (int st0 = 0; st0 < ST_TOT; st0 += tiles_c){
        int tc = ST_TOT - st0; if (tc > tiles_c) tc = tiles_c;
        k_phaseA<<<32 * tc, 1024, 0, stream>>>(row_order, goff, gcnt, ell, t0buf, basis, st0);
        k_phaseB<<<tc * 512, 256, 0, stream>>>(basis, t0buf, wtab, bias, out, st0);
    }
}

// Round 9
// 612.578 us; speedup vs baseline: 1.0114x; 1.0040x over previous
//
#include <hip/hip_runtime.h>
#include <stdint.h>

#define V_N    4096
#define NNZ_N  36864
#define S_N    216        // X*Y*Z = 6*6*6
#define ST_TOT 27         // S_N / 8
#define PLANES 256        // K * FIN
#define BPLANES 224       // basis planes per stl (k=1..7)

typedef float  f32x2 __attribute__((ext_vector_type(2)));
typedef float  f32x4 __attribute__((ext_vector_type(4)));
typedef short  s16x4 __attribute__((ext_vector_type(4)));
typedef short  s16x8 __attribute__((ext_vector_type(8)));

static __device__ __forceinline__ unsigned short f2bf(float f){
    union { float f; unsigned u; } x; x.f = f;
    unsigned r = x.u + 0x7FFFu + ((x.u >> 16) & 1u);   // round-to-nearest-even
    return (unsigned short)(r >> 16);
}
static __device__ __forceinline__ unsigned packbf(float lo, float hi){
    unsigned r;
    asm("v_cvt_pk_bf16_f32 %0, %1, %2" : "=v"(r) : "v"(lo), "v"(hi));
    return r;
}
static __device__ __forceinline__ void pkfma(f32x2& acc, f32x2 c, f32x2 vv){
    asm("v_pk_fma_f32 %0, %1, %2, %0" : "+v"(acc) : "v"(c), "v"(vv));
}
#define BLO(u) __uint_as_float((u) << 16)
#define BHI(u) __uint_as_float((u) & 0xFFFF0000u)

// tr_b16-staging permutation (identical to verified r7 kernel):
// b(p, vrr) = ((vrr>>2)<<10) | (((vrr>>1)&1)<<9) | ((p>>5)<<6) | (((p>>2)&1)<<5)
//           | (((p>>3)&3)<<3) | ((p&3)<<1) | (vrr&1)
static __device__ __forceinline__ int bperm(int p, int vrr){
    return ((vrr >> 2) << 10) + (((vrr >> 1) & 1) << 9)
         + ((p >> 5) << 6) + (((p >> 2) & 1) << 5) + (((p >> 3) & 3) << 3)
         + ((p & 3) << 1) + (vrr & 1);
}

// ---------------- k_prep: fused hist + degree-sort + group offsets (1 block) --------
__global__ __launch_bounds__(1024) void k_prep(
    const int* __restrict__ rows, int* __restrict__ row_order,
    int* __restrict__ sp, int* __restrict__ gcnt, int* __restrict__ goff,
    int* __restrict__ rcur)
{
    __shared__ int cnt[4096];
    __shared__ int c2[4096];
    __shared__ int dh[64];
    int t = threadIdx.x;
    #pragma unroll
    for (int i = 0; i < 4; ++i) cnt[t + i*1024] = 0;
    if (t < 64) dh[t] = 0;
    __syncthreads();
    for (int e = t; e < NNZ_N; e += 1024) atomicAdd(&cnt[rows[e]], 1);
    __syncthreads();
    #pragma unroll
    for (int i = 0; i < 4; ++i){
        int d = cnt[t + i*1024]; if (d > 63) d = 63;
        atomicAdd(&dh[d], 1);
    }
    __syncthreads();
    if (t == 0){ int s = 0; for (int i = 0; i < 64; ++i){ int x = dh[i]; dh[i] = s; s += x; } }
    __syncthreads();
    #pragma unroll
    for (int i = 0; i < 4; ++i){
        int v = t + i*1024;
        int d = cnt[v]; int db = d > 63 ? 63 : d;
        int pos = atomicAdd(&dh[db], 1);
        row_order[pos] = v; sp[v] = pos; c2[pos] = d;
    }
    #pragma unroll
    for (int i = 0; i < 4; ++i) rcur[t + i*1024] = 0;
    __syncthreads();
    if (t == 0){
        int off = 0;
        for (int g = 0; g < 64; ++g){
            int d = c2[g*64 + 63]; if (d > 64) d = 64;
            gcnt[g] = d; goff[g] = off; off += (d + 3) * 64;
        }
    }
}

// ---------------- k_fill2: ELL fill (blocks 0..143) + W pack (blocks 144..175) ------
__global__ void k_fill2(const int* __restrict__ rows, const int* __restrict__ cols,
                        const float* __restrict__ vals, const int* __restrict__ sp,
                        const int* __restrict__ gcnt, const int* __restrict__ goff,
                        int* __restrict__ rcur, unsigned* __restrict__ ell,
                        const float* __restrict__ w, unsigned short* __restrict__ wtab)
{
    int bid = blockIdx.x, t = threadIdx.x;
    if (bid < 144){
        int e = bid * 256 + t;
        if (e < NNZ_N){
            int r = rows[e]; int s = sp[r]; int g = s >> 6; int l = s & 63;
            int i = atomicAdd(&rcur[r], 1);
            if (i < gcnt[g])
                ell[goff[g] + i * 64 + l] =
                    ((unsigned)cols[e] << 4) | ((unsigned)f2bf(vals[e]) << 16);
        }
    } else {
        int idx = (bid - 144) * 256 + t;   // 0..8191
        int slot = idx >> 3, j = idx & 7;
        int ki = slot >> 7, nh = (slot >> 6) & 1, l = slot & 63;
        int p  = ki * 32 + ((l >> 4) << 3) + j;
        int fo = nh * 16 + (l & 15);
        wtab[idx] = f2bf(w[p * 32 + fo]);
    }
}

// ---------------- k_pre: input transpose -> t0 tiles (bf16) ----------------
// t0t layout: t0t[(st*512 + vb)*256 + f*8 + vrr]  (4 KB contiguous per (st,vb) tile)
__global__ __launch_bounds__(256, 4) void k_pre(
    const float* __restrict__ in, uint4* __restrict__ t0t)
{
    __shared__ unsigned short lds[64 * 218];   // 27.3 KB, row stride 436 B
    int bid = blockIdx.x;
    int f = bid >> 6, vblk = bid & 63;
    int t = threadIdx.x;
    const f32x4* src = (const f32x4*)(in + ((size_t)f * V_N + vblk * 64) * S_N);

    #pragma unroll
    for (int it = 0; it < 14; ++it){
        int idx = t + it * 256;                 // float4 index, 0..3455
        if (idx < 3456){
            int vloc = (int)(((unsigned)idx * 4855u) >> 18);   // idx / 54
            int s4   = idx - vloc * 54;
            f32x4 a = __builtin_nontemporal_load(&src[idx]);
            uint2 q; q.x = packbf(a.x, a.y); q.y = packbf(a.z, a.w);
            *(uint2*)((char*)lds + vloc * 436 + s4 * 8) = q;
        }
    }
    __syncthreads();
    #pragma unroll
    for (int it = 0; it < 7; ++it){
        int idx = t + it * 256;
        if (idx < ST_TOT * 64){
            int stl = idx >> 6, vl = idx & 63;
            uint4 q = *(const uint4*)((const char*)lds + vl * 436 + stl * 16);
            t0t[((size_t)(stl * 512 + vblk * 8 + (vl >> 3))) * 256 + f * 8 + (vl & 7)] = q;
        }
    }
}

// ---------------- Phase A: LDS-resident Chebyshev recurrence ----------------
// basis3 (chunk-local): basis3[(stl*512 + vb)*1792 + ((k-1)*32+f)*8 + vrr]
__global__ __launch_bounds__(1024, 8) void k_phaseA(
    const int* __restrict__ row_order,
    const int* __restrict__ goff, const int* __restrict__ gcnt,
    const unsigned* __restrict__ ell, const uint4* __restrict__ t0t,
    uint4* __restrict__ basis3, int st0)
{
    __shared__ uint4 T4[V_N];        // 64 KB
    int f   = blockIdx.x & 31;
    int stl = blockIdx.x >> 5;       // chunk-local
    int st_g = st0 + stl;            // global
    int t = threadIdx.x;

    // T0 from t0t (8x128 B chunks per wave-instr)
    const uint4* t0p = t0t + ((size_t)st_g << 9) * 256 + f * 8;
    #pragma unroll
    for (int rr = 0; rr < 4; ++rr){
        int v = t + rr * 1024;
        T4[v] = t0p[(size_t)(v >> 3) * 256 + (v & 7)];
    }
    __syncthreads();

    // wave w owns groups {w, w+16, w+32, w+48}  (strided => balanced degrees)
    int w = t >> 6, lane = t & 63;
    int vr[4], gba[4], gcn[4];
    #pragma unroll
    for (int rr = 0; rr < 4; ++rr){
        int g = w + rr * 16;
        vr[rr]  = row_order[g * 64 + lane];
        gba[rr] = goff[g] + lane;
        gcn[rr] = __builtin_amdgcn_readfirstlane(gcnt[g]);
    }
    uint4 tm2[4];
    #pragma unroll
    for (int rr = 0; rr < 4; ++rr) tm2[rr] = T4[vr[rr]];   // T0 own rows

    for (int k = 1; k < 8; ++k){
        uint4 nst[4];
        #pragma unroll
        for (int rr = 0; rr < 4; ++rr){
            f32x2 ac0 = {0,0}, ac1 = {0,0}, ac2 = {0,0}, ac3 = {0,0};
            const unsigned* ep = ell + gba[rr];
            int cnt = gcn[rr];
            unsigned u0 = ep[0];
            unsigned u1 = ep[64];
            for (int i = 0; i < cnt; i += 2){
                unsigned n0 = ep[(i + 2) << 6];     // prefetch next pair (pad rows are 0)
                unsigned n1 = ep[(i + 3) << 6];
                uint4 q0 = *(const uint4*)((const char*)T4 + (u0 & 0xFFF0u));
                uint4 q1 = *(const uint4*)((const char*)T4 + (u1 & 0xFFF0u));
                float v0 = __uint_as_float(u0 & 0xFFFF0000u);
                float v1 = __uint_as_float(u1 & 0xFFFF0000u);
                f32x2 vv0 = {v0, v0};
                f32x2 vv1 = {v1, v1};
                f32x2 c;
                c.x = BLO(q0.x); c.y = BHI(q0.x);  pkfma(ac0, c, vv0);
                c.x = BLO(q0.y); c.y = BHI(q0.y);  pkfma(ac1, c, vv0);
                c.x = BLO(q0.z); c.y = BHI(q0.z);  pkfma(ac2, c, vv0);
                c.x = BLO(q0.w); c.y = BHI(q0.w);  pkfma(ac3, c, vv0);
                c.x = BLO(q1.x); c.y = BHI(q1.x);  pkfma(ac0, c, vv1);
                c.x = BLO(q1.y); c.y = BHI(q1.y);  pkfma(ac1, c, vv1);
                c.x = BLO(q1.z); c.y = BHI(q1.z);  pkfma(ac2, c, vv1);
                c.x = BLO(q1.w); c.y = BHI(q1.w);  pkfma(ac3, c, vv1);
                u0 = n0; u1 = n1;
            }
            float a0 = ac0.x, a1 = ac0.y, a2 = ac1.x, a3 = ac1.y;
            float a4 = ac2.x, a5 = ac2.y, a6 = ac3.x, a7 = ac3.y;
            if (k > 1){
                a0 = fmaf(2.f, a0, -BLO(tm2[rr].x));  a1 = fmaf(2.f, a1, -BHI(tm2[rr].x));
                a2 = fmaf(2.f, a2, -BLO(tm2[rr].y));  a3 = fmaf(2.f, a3, -BHI(tm2[rr].y));
                a4 = fmaf(2.f, a4, -BLO(tm2[rr].z));  a5 = fmaf(2.f, a5, -BHI(tm2[rr].z));
                a6 = fmaf(2.f, a6, -BLO(tm2[rr].w));  a7 = fmaf(2.f, a7, -BHI(tm2[rr].w));
            }
            nst[rr].x = packbf(a0, a1); nst[rr].y = packbf(a2, a3);
            nst[rr].z = packbf(a4, a5); nst[rr].w = packbf(a6, a7);
        }
        #pragma unroll
        for (int rr = 0; rr < 4; ++rr) tm2[rr] = T4[vr[rr]];   // T_{k-1} own rows
        __syncthreads();
        #pragma unroll
        for (int rr = 0; rr < 4; ++rr) T4[vr[rr]] = nst[rr];   // LDS <- T_k
        __syncthreads();
        // basis write of T_k from LDS: 8x128 B contiguous chunks per wave-instr
        uint4* bp = basis3 + ((size_t)stl << 9) * 1792 + ((k - 1) * 32 + f) * 8;
        #pragma unroll
        for (int rr = 0; rr < 4; ++rr){
            int v = t + rr * 1024;
            bp[(size_t)(v >> 3) * 1792 + (v & 7)] = T4[v];
        }
    }
}

// ---------------- Phase B: projection GEMM (MFMA bf16), 64 rows/block -----------
// stage: contiguous tile load (t0t 4 KB + basis3 28 KB) -> permuted ds_write
__global__ __launch_bounds__(256, 3) void k_phaseB(
    const uint4* __restrict__ basis3, const uint4* __restrict__ t0t,
    const uint4* __restrict__ wtab, const float* __restrict__ bias,
    float* __restrict__ out, int st0)
{
    __shared__ uint4 A[2048];      // 32 KB; reused as outT in epilogue
    int t = threadIdx.x;
    int tile = blockIdx.x;
    int stl = tile >> 9, vb = tile & 511;
    int st_g = st0 + stl;
    int lane = t & 63, w = t >> 6;

    // W fragments straight from L2-resident wtab (coalesced per-lane reads)
    const s16x8* wp = (const s16x8*)wtab;
    s16x8 wf[16];
    #pragma unroll
    for (int q = 0; q < 16; ++q) wf[q] = wp[(q << 6) + lane];

    // contiguous tile loads + permuted LDS scatter
    {
        const uint4* srcT = t0t + ((size_t)(st_g * 512 + vb)) * 256;
        uint4 q0 = srcT[t];
        int p0 = t >> 3, vr0 = t & 7;
        A[bperm(p0, vr0)] = q0;
        const uint4* srcB = basis3 + ((size_t)(stl * 512 + vb)) * 1792;
        #pragma unroll
        for (int it = 0; it < 7; ++it){
            int g = it * 256 + t;
            uint4 q = srcB[g];
            int p = 32 + (g >> 3), vrr = g & 7;
            A[bperm(p, vrr)] = q;
        }
    }
    __syncthreads();

    unsigned abase = (unsigned)(size_t)(&A[0]) + ((w >> 1) << 14) + ((w & 1) << 13) + (lane << 3);
    f32x4 acc0 = {0,0,0,0}, acc1 = {0,0,0,0};
    #pragma unroll
    for (int ki = 0; ki < 8; ++ki){
        s16x4 x0, x1;
        unsigned a0 = abase + (ki << 10);
        asm volatile("ds_read_b64_tr_b16 %0, %2\n\t"
                     "ds_read_b64_tr_b16 %1, %2 offset:512\n\t"
                     "s_waitcnt lgkmcnt(0)"
                     : "=&v"(x0), "=&v"(x1) : "v"(a0));
        __builtin_amdgcn_sched_barrier(0);
        s16x8 af;
        af[0]=x0[0]; af[1]=x0[1]; af[2]=x0[2]; af[3]=x0[3];
        af[4]=x1[0]; af[5]=x1[1]; af[6]=x1[2]; af[7]=x1[3];
        acc0 = __builtin_amdgcn_mfma_f32_16x16x32_bf16(af, wf[2*ki+0], acc0, 0, 0, 0);
        acc1 = __builtin_amdgcn_mfma_f32_16x16x32_bf16(af, wf[2*ki+1], acc1, 0, 0, 0);
    }

    // stage 64x32 output tile into A region, then fully-coalesced store
    __syncthreads();
    float* outT = (float*)&A[0];     // [fo][68] floats (8.7 KB)
    {
        int rl0 = w * 16 + ((lane >> 4) << 2);
        int foA = lane & 15, foB = 16 + (lane & 15);
        float2 p;
        p.x = acc0[0]; p.y = acc0[1]; *(float2*)&outT[foA*68 + rl0]     = p;
        p.x = acc0[2]; p.y = acc0[3]; *(float2*)&outT[foA*68 + rl0 + 2] = p;
        p.x = acc1[0]; p.y = acc1[1]; *(float2*)&outT[foB*68 + rl0]     = p;
        p.x = acc1[2]; p.y = acc1[3]; *(float2*)&outT[foB*68 + rl0 + 2] = p;
    }
    __syncthreads();
    {
        int fo = t >> 3;
        int rl = (t & 7) << 3;            // 8 rows = 1 v, all 8 sl
        float bs = bias[fo];
        float2 q0 = *(const float2*)&outT[fo*68 + rl];
        float2 q1 = *(const float2*)&outT[fo*68 + rl + 2];
        float2 q2 = *(const float2*)&outT[fo*68 + rl + 4];
        float2 q3 = *(const float2*)&outT[fo*68 + rl + 6];
        int v = vb * 8 + (t & 7);
        float* gb = out + ((size_t)fo * V_N + v) * S_N + st_g * 8;
        f32x4 o;
        o.x = q0.x + bs; o.y = q0.y + bs; o.z = q1.x + bs; o.w = q1.y + bs;
        __builtin_nontemporal_store(o, (f32x4*)gb);
        o.x = q2.x + bs; o.y = q2.y + bs; o.z = q3.x + bs; o.w = q3.y + bs;
        __builtin_nontemporal_store(o, (f32x4*)(gb + 4));
    }
}

// ---------------- host ----------------
extern "C" void kernel_launch(void* const* d_in, const int* in_sizes, int n_in,
                              void* d_out, int out_size, void* d_ws, size_t ws_size,
                              hipStream_t stream)
{
    const float* inp  = (const float*)d_in[0];
    const float* wgt  = (const float*)d_in[1];
    const float* bias = (const float*)d_in[2];
    const float* vals = (const float*)d_in[3];
    const int*   rows = (const int*)d_in[4];
    const int*   cols = (const int*)d_in[5];
    float* out = (float*)d_out;

    char* ws = (char*)d_ws;
    size_t o = 0;
    auto alloc = [&](size_t bytes) -> void* {
        void* p = ws + o; o = (o + bytes + 255) & ~(size_t)255; return p;
    };
    const size_t ELL_B = (size_t)64 * 67 * 64 * 4;   // 1.05 MB hard cap
    int* row_order = (int*)alloc(4096 * 4);
    int* sp        = (int*)alloc(4096 * 4);
    int* gcnt      = (int*)alloc(64 * 4);
    int* goff      = (int*)alloc(64 * 4);
    int* rcur      = (int*)alloc(4096 * 4);
    unsigned* ell  = (unsigned*)alloc(ELL_B);
    uint4* wtab    = (uint4*)alloc(8192 * 2);
    uint4* t0buf   = (uint4*)alloc((size_t)ST_TOT * 512 * 256 * 16);   // 56.6 MB
    size_t used = o;

    size_t per_st = (size_t)512 * 1792 * 16;         // 14.68 MB per s8-tile
    size_t avail = (ws_size > used) ? (ws_size - used) : 0;
    int tiles_c = (int)(avail / per_st);
    if (tiles_c > 16) tiles_c = 16;                  // {16,11} chunk pattern
    if (tiles_c < 1) tiles_c = 1;
    uint4* basis = (uint4*)alloc(per_st * tiles_c);  // chunk-local, region-reused

    hipMemsetAsync(ell, 0, ELL_B, stream);
    k_prep  <<<1, 1024, 0, stream>>>(rows, row_order, sp, gcnt, goff, rcur);
    k_fill2 <<<176, 256, 0, stream>>>(rows, cols, vals, sp, gcnt, goff, rcur, ell,
                                      wgt, (unsigned short*)wtab);
    k_pre   <<<2048, 256, 0, stream>>>(inp, t0buf);

    for (int st0 = 0; st0 < ST_TOT; st0 += tiles_c){
        int tc = ST_TOT - st0; if (tc > tiles_c) tc = tiles_c;
        k_phaseA<<<32 * tc, 1024, 0, stream>>>(row_order, goff, gcnt, ell, t0buf, basis, st0);
        k_phaseB<<<tc * 512, 256, 0, stream>>>(basis, t0buf, wtab, bias, out, st0);
    }
}